// Round 1
// baseline (264.429 us; speedup 1.0000x reference)
//
#include <hip/hip_runtime.h>
#include <cstdint>

typedef unsigned short u16;
typedef __bf16 bf16x8 __attribute__((ext_vector_type(8)));
typedef float f32x4 __attribute__((ext_vector_type(4)));

__device__ __forceinline__ float bf2f(u16 h) {
  union { unsigned int u; float f; } v; v.u = ((unsigned int)h) << 16; return v.f;
}
__device__ __forceinline__ u16 f2bf(float f) {
  union { float f; unsigned int u; } v; v.f = f;
  unsigned int u = v.u;
  return (u16)((u + 0x7FFFu + ((u >> 16) & 1u)) >> 16);  // RNE, inputs are finite
}

__device__ __forceinline__ void ld_lds16(const void* g, void* l) {
  __builtin_amdgcn_global_load_lds(
      (const __attribute__((address_space(1))) unsigned int*)g,
      (__attribute__((address_space(3))) unsigned int*)l, 16, 0, 0);
}

// ---------------------------------------------------------------------------
// Shared 128x128-tile bf16 GEMM, C = A * B^T  (A: MrowsxKd, B: NcolsxKd, both
// row-major bf16, Kd % 64 == 0). MODE 0: epilogue = scale 1/32, store bf16 S,
// atomicAdd row sums of exp(s) into L1. MODE 1: epilogue = scale row by
// 1/L2[row], store fp32.
// ---------------------------------------------------------------------------
template <int MODE>
__global__ __launch_bounds__(256, 2) void gemm_kernel(
    const u16* __restrict__ A, const u16* __restrict__ B,
    void* __restrict__ Cout, float* __restrict__ L1,
    const float* __restrict__ L2, int Kd, int Ncols)
{
  __shared__ u16 As[128 * 64];   // 16 KB, row-major 128 rows x 64 bf16 (XOR-swizzled 16B chunks)
  __shared__ u16 Bs[128 * 64];

  const int tid  = threadIdx.x;
  const int lane = tid & 63;
  const int w    = tid >> 6;   // wave 0..3
  const int wr   = w >> 1;     // wave row 0..1 (64-row half)
  const int wc   = w & 1;      // wave col 0..1 (64-col half)
  const int quad = lane >> 4;
  const int cIn  = lane & 15;

  const int rowBlk = blockIdx.y * 128;
  const int colBlk = blockIdx.x * 128;

  // staging: each global_load_lds moves 64 lanes x 16B = 8 rows x 128B
  const int lrow   = lane >> 3;            // row within 8-row group
  const int gchunk = (lane & 7) ^ lrow;    // XOR swizzle: LDS chunk c holds A[row][c ^ (row&7)]

  f32x4 acc[4][4];
  #pragma unroll
  for (int i = 0; i < 4; ++i)
    #pragma unroll
    for (int j = 0; j < 4; ++j) acc[i][j] = {0.f, 0.f, 0.f, 0.f};

  for (int k0 = 0; k0 < Kd; k0 += 64) {
    #pragma unroll
    for (int t = 0; t < 4; ++t) {
      int rg = w * 4 + t;
      const u16* ga = A + (size_t)(rowBlk + rg * 8 + lrow) * Kd + k0 + gchunk * 8;
      const u16* gb = B + (size_t)(colBlk + rg * 8 + lrow) * Kd + k0 + gchunk * 8;
      ld_lds16(ga, &As[rg * 512]);
      ld_lds16(gb, &Bs[rg * 512]);
    }
    __syncthreads();   // compiler emits vmcnt(0) drain before barrier

    #pragma unroll
    for (int ks = 0; ks < 2; ++ks) {
      bf16x8 af[4], bf[4];
      #pragma unroll
      for (int mi = 0; mi < 4; ++mi) {
        int row = wr * 64 + mi * 16 + cIn;
        int ch  = (ks * 4 + quad) ^ (row & 7);
        af[mi]  = *(const bf16x8*)&As[row * 64 + ch * 8];
      }
      #pragma unroll
      for (int ni = 0; ni < 4; ++ni) {
        int row = wc * 64 + ni * 16 + cIn;
        int ch  = (ks * 4 + quad) ^ (row & 7);
        bf[ni]  = *(const bf16x8*)&Bs[row * 64 + ch * 8];
      }
      #pragma unroll
      for (int mi = 0; mi < 4; ++mi)
        #pragma unroll
        for (int ni = 0; ni < 4; ++ni)
          acc[mi][ni] = __builtin_amdgcn_mfma_f32_16x16x32_bf16(
              af[mi], bf[ni], acc[mi][ni], 0, 0, 0);
    }
    __syncthreads();
  }

  // C/D layout (verified m89/m91): col = lane&15, row = quad*4 + reg
  if (MODE == 0) {
    u16* S = (u16*)Cout;
    const float scale = 0.03125f;  // 1/sqrt(1024)
    #pragma unroll
    for (int mi = 0; mi < 4; ++mi) {
      float rs[4] = {0.f, 0.f, 0.f, 0.f};
      #pragma unroll
      for (int ni = 0; ni < 4; ++ni) {
        int col = colBlk + wc * 64 + ni * 16 + cIn;
        #pragma unroll
        for (int r = 0; r < 4; ++r) {
          int row = rowBlk + wr * 64 + mi * 16 + quad * 4 + r;
          u16 sb = f2bf(acc[mi][ni][r] * scale);
          S[(size_t)row * Ncols + col] = sb;
          rs[r] += __expf(bf2f(sb));   // exp of the bf16-rounded value for L1 consistency
        }
      }
      #pragma unroll
      for (int m = 1; m < 16; m <<= 1)
        #pragma unroll
        for (int r = 0; r < 4; ++r) rs[r] += __shfl_xor(rs[r], m, 64);
      if (cIn == 0) {
        #pragma unroll
        for (int r = 0; r < 4; ++r)
          atomicAdd(&L1[rowBlk + wr * 64 + mi * 16 + quad * 4 + r], rs[r]);
      }
    }
  } else {
    float* Out = (float*)Cout;
    #pragma unroll
    for (int mi = 0; mi < 4; ++mi) {
      #pragma unroll
      for (int r = 0; r < 4; ++r) {
        int row   = rowBlk + wr * 64 + mi * 16 + quad * 4 + r;
        float inv = 1.0f / L2[row];
        #pragma unroll
        for (int ni = 0; ni < 4; ++ni) {
          int col = colBlk + wc * 64 + ni * 16 + cIn;
          Out[(size_t)row * Ncols + col] = acc[mi][ni][r] * inv;
        }
      }
    }
  }
}

// fp32 -> bf16 cast, vectorized
__global__ void cvt_f32_bf16(const float* __restrict__ in, u16* __restrict__ out, int n4) {
  int i = blockIdx.x * blockDim.x + threadIdx.x;
  if (i < n4) {
    float4 v = ((const float4*)in)[i];
    ushort4 o;
    o.x = f2bf(v.x); o.y = f2bf(v.y); o.z = f2bf(v.z); o.w = f2bf(v.w);
    ((ushort4*)out)[i] = o;
  }
}

// V [R x C] fp32 -> Vt [C x R] bf16 (LDS tile transpose, +1 pad)
__global__ void transpose_cvt(const float* __restrict__ V, u16* __restrict__ Vt, int R, int C) {
  __shared__ float tile[32][33];
  int c0 = blockIdx.x * 32, r0 = blockIdx.y * 32;
  int tx = threadIdx.x, ty = threadIdx.y;  // blockDim (32, 8)
  #pragma unroll
  for (int i = 0; i < 32; i += 8)
    tile[ty + i][tx] = V[(size_t)(r0 + ty + i) * C + c0 + tx];
  __syncthreads();
  #pragma unroll
  for (int i = 0; i < 32; i += 8)
    Vt[(size_t)(c0 + ty + i) * R + r0 + tx] = f2bf(tile[tx][ty + i]);
}

// second softmax prep: p = exp(exp(s)/L1 * mask) in-place over S (bf16),
// row sums -> L2. One block per row; t = probs1*mask in [0,1], no max needed.
__global__ __launch_bounds__(256) void softmax2_kernel(
    u16* __restrict__ S, const float* __restrict__ mask,
    const float* __restrict__ L1, float* __restrict__ L2, int M)
{
  int row = blockIdx.x;
  float inv = 1.0f / L1[row];
  u16* srow = S + (size_t)row * M;
  const float* mrow = mask + (size_t)row * M;
  float lsum = 0.f;
  for (int base = threadIdx.x * 16; base < M; base += blockDim.x * 16) {
    u16 sl[16];
    *(uint4*)(sl)     = *(const uint4*)(srow + base);
    *(uint4*)(sl + 8) = *(const uint4*)(srow + base + 8);
    float mv[16];
    #pragma unroll
    for (int q = 0; q < 4; ++q)
      *(float4*)(mv + q * 4) = *(const float4*)(mrow + base + q * 4);
    #pragma unroll
    for (int j = 0; j < 16; ++j) {
      float t = __expf(bf2f(sl[j])) * inv * mv[j];
      float p = __expf(t);
      lsum += p;
      sl[j] = f2bf(p);
    }
    *(uint4*)(srow + base)     = *(uint4*)(sl);
    *(uint4*)(srow + base + 8) = *(uint4*)(sl + 8);
  }
  #pragma unroll
  for (int m = 1; m < 64; m <<= 1) lsum += __shfl_xor(lsum, m, 64);
  __shared__ float wred[4];
  if ((threadIdx.x & 63) == 0) wred[threadIdx.x >> 6] = lsum;
  __syncthreads();
  if (threadIdx.x == 0) L2[row] = wred[0] + wred[1] + wred[2] + wred[3];
}

extern "C" void kernel_launch(void* const* d_in, const int* in_sizes, int n_in,
                              void* d_out, int out_size, void* d_ws, size_t ws_size,
                              hipStream_t stream) {
  const float* H    = (const float*)d_in[0];
  const float* Kin  = (const float*)d_in[1];
  const float* V    = (const float*)d_in[2];
  const float* mask = (const float*)d_in[3];
  float* out = (float*)d_out;

  const int N = 4096, M = 4096, D = 1024;

  // ws layout: Hb 8MB | Kb 8MB | Vt 8MB | S 32MB | L1 16KB | L2 16KB  (~58.8MB)
  char* ws = (char*)d_ws;
  u16*   Hb = (u16*)(ws);
  u16*   Kb = (u16*)(ws + (8ull << 20));
  u16*   Vt = (u16*)(ws + (16ull << 20));
  u16*   S  = (u16*)(ws + (24ull << 20));
  float* L1 = (float*)(ws + (56ull << 20));
  float* L2 = (float*)(ws + (56ull << 20) + 16384);

  hipMemsetAsync(L1, 0, 32768, stream);  // zero L1+L2 (ws is poisoned each call)

  int n4 = N * D / 4;
  cvt_f32_bf16<<<dim3((n4 + 255) / 256), dim3(256), 0, stream>>>(H, Hb, n4);
  cvt_f32_bf16<<<dim3((n4 + 255) / 256), dim3(256), 0, stream>>>(Kin, Kb, n4);
  transpose_cvt<<<dim3(D / 32, M / 32), dim3(32, 8), 0, stream>>>(V, Vt, M, D);

  // S = H*K^T/32 (bf16), L1[i] = sum_j exp(S_ij)
  gemm_kernel<0><<<dim3(M / 128, N / 128), dim3(256), 0, stream>>>(
      Hb, Kb, S, L1, nullptr, D, M);
  // S <- exp(exp(S)/L1 * mask), L2 = row sums
  softmax2_kernel<<<dim3(N), dim3(256), 0, stream>>>(S, mask, L1, L2, M);
  // out = (S @ Vt^T) / L2
  gemm_kernel<1><<<dim3(D / 128, N / 128), dim3(256), 0, stream>>>(
      S, Vt, out, nullptr, L2, M, D);
}

// Round 2
// 260.298 us; speedup vs baseline: 1.0159x; 1.0159x over previous
//
#include <hip/hip_runtime.h>
#include <cstdint>

typedef unsigned short u16;
typedef __bf16 bf16x8 __attribute__((ext_vector_type(8)));
typedef float f32x4 __attribute__((ext_vector_type(4)));

__device__ __forceinline__ float bf2f(u16 h) {
  union { unsigned int u; float f; } v; v.u = ((unsigned int)h) << 16; return v.f;
}
__device__ __forceinline__ u16 f2bf(float f) {
  union { float f; unsigned int u; } v; v.f = f;
  unsigned int u = v.u;
  return (u16)((u + 0x7FFFu + ((u >> 16) & 1u)) >> 16);  // RNE, finite inputs
}

__device__ __forceinline__ void ld_lds16(const void* g, void* l) {
  __builtin_amdgcn_global_load_lds(
      (const __attribute__((address_space(1))) unsigned int*)g,
      (__attribute__((address_space(3))) unsigned int*)l, 16, 0, 0);
}

// ---------------------------------------------------------------------------
// 128x128-tile bf16 GEMM, C = A * B^T over k-range [kb,ke).
// A row-major [.. x ldA], B row-major [.. x ldB], bf16.
// MODE 0: full K; epilogue scales 1/32, stores bf16 S, atomicAdds exp-rowsums
//         into L1. Grid 1024 flat; XCD region = 16 rows x 8 cols.
// MODE 1: split-K (4 slices of 1024); epilogue atomicAdds acc/L2[row] into
//         fp32 out (pre-zeroed). Grid 1024 flat; XCD region = k-pure,
//         16 rows x 8 cols (2 XCDs per k-slice).
// ---------------------------------------------------------------------------
template <int MODE>
__global__ __launch_bounds__(256, 2) void gemm_kernel(
    const u16* __restrict__ A, const u16* __restrict__ B,
    void* __restrict__ Cout, float* __restrict__ L1,
    const float* __restrict__ L2, int ldA, int ldB, int ldC)
{
  __shared__ u16 As[128 * 64];   // 16 KB (XOR-swizzled 16B chunks)
  __shared__ u16 Bs[128 * 64];

  const int tid  = threadIdx.x;
  const int lane = tid & 63;
  const int w    = tid >> 6;
  const int wr   = w >> 1;
  const int wc   = w & 1;
  const int quad = lane >> 4;
  const int cIn  = lane & 15;

  // XCD-aware swizzle: dispatch round-robins flat id across 8 XCDs.
  const int flat = blockIdx.x;
  const int xcd  = flat & 7;
  const int i    = flat >> 3;          // 0..127 within XCD
  int rowBlk, colBlk, kb, ke;
  if (MODE == 0) {
    // 32x32 tile grid; XCD region 16 rows x 8 cols (A 4MB + B 2MB per XCD)
    rowBlk = ((xcd >> 2) * 16 + (i & 15)) * 128;
    colBlk = ((xcd & 3) * 8 + (i >> 4)) * 128;
    kb = 0; ke = 1024;
  } else {
    // 32 rows x 8 cols x 4 kslices; XCD k-pure: 2 XCDs cover 32x8 per slice
    rowBlk = (((xcd & 1) * 16) + (i & 15)) * 128;
    colBlk = (i >> 4) * 128;
    kb = (xcd >> 1) * 1024; ke = kb + 1024;
  }

  const int lrow   = lane >> 3;
  const int gchunk = (lane & 7) ^ lrow;   // XOR swizzle for LDS bank spread

  f32x4 acc[4][4];
  #pragma unroll
  for (int a = 0; a < 4; ++a)
    #pragma unroll
    for (int b = 0; b < 4; ++b) acc[a][b] = {0.f, 0.f, 0.f, 0.f};

  for (int k0 = kb; k0 < ke; k0 += 64) {
    #pragma unroll
    for (int t = 0; t < 4; ++t) {
      int rg = w * 4 + t;
      const u16* ga = A + (size_t)(rowBlk + rg * 8 + lrow) * ldA + k0 + gchunk * 8;
      const u16* gb = B + (size_t)(colBlk + rg * 8 + lrow) * ldB + k0 + gchunk * 8;
      ld_lds16(ga, &As[rg * 512]);
      ld_lds16(gb, &Bs[rg * 512]);
    }
    __syncthreads();

    #pragma unroll
    for (int ks = 0; ks < 2; ++ks) {
      bf16x8 af[4], bfr[4];
      #pragma unroll
      for (int mi = 0; mi < 4; ++mi) {
        int row = wr * 64 + mi * 16 + cIn;
        int ch  = (ks * 4 + quad) ^ (row & 7);
        af[mi]  = *(const bf16x8*)&As[row * 64 + ch * 8];
      }
      #pragma unroll
      for (int ni = 0; ni < 4; ++ni) {
        int row = wc * 64 + ni * 16 + cIn;
        int ch  = (ks * 4 + quad) ^ (row & 7);
        bfr[ni] = *(const bf16x8*)&Bs[row * 64 + ch * 8];
      }
      #pragma unroll
      for (int mi = 0; mi < 4; ++mi)
        #pragma unroll
        for (int ni = 0; ni < 4; ++ni)
          acc[mi][ni] = __builtin_amdgcn_mfma_f32_16x16x32_bf16(
              af[mi], bfr[ni], acc[mi][ni], 0, 0, 0);
    }
    __syncthreads();
  }

  // C/D layout: col = lane&15, row = quad*4 + reg
  if (MODE == 0) {
    u16* S = (u16*)Cout;
    const float scale = 0.03125f;  // 1/sqrt(1024)
    #pragma unroll
    for (int mi = 0; mi < 4; ++mi) {
      float rs[4] = {0.f, 0.f, 0.f, 0.f};
      #pragma unroll
      for (int ni = 0; ni < 4; ++ni) {
        int col = colBlk + wc * 64 + ni * 16 + cIn;
        #pragma unroll
        for (int r = 0; r < 4; ++r) {
          int row = rowBlk + wr * 64 + mi * 16 + quad * 4 + r;
          u16 sb = f2bf(acc[mi][ni][r] * scale);
          S[(size_t)row * ldC + col] = sb;
          rs[r] += __expf(bf2f(sb));
        }
      }
      #pragma unroll
      for (int m = 1; m < 16; m <<= 1)
        #pragma unroll
        for (int r = 0; r < 4; ++r) rs[r] += __shfl_xor(rs[r], m, 64);
      if (cIn == 0) {
        #pragma unroll
        for (int r = 0; r < 4; ++r)
          atomicAdd(&L1[rowBlk + wr * 64 + mi * 16 + quad * 4 + r], rs[r]);
      }
    }
  } else {
    float* Out = (float*)Cout;
    #pragma unroll
    for (int mi = 0; mi < 4; ++mi) {
      #pragma unroll
      for (int r = 0; r < 4; ++r) {
        int row   = rowBlk + wr * 64 + mi * 16 + quad * 4 + r;
        float inv = 1.0f / L2[row];
        #pragma unroll
        for (int ni = 0; ni < 4; ++ni) {
          int col = colBlk + wc * 64 + ni * 16 + cIn;
          atomicAdd(&Out[(size_t)row * ldC + col], acc[mi][ni][r] * inv);
        }
      }
    }
  }
}

// Fused prep: blocks [0,4096) cvt H, [4096,8192) cvt K, [8192,12288) transpose V.
__global__ __launch_bounds__(256) void prep_kernel(
    const float* __restrict__ H, const float* __restrict__ Kin,
    const float* __restrict__ V, u16* __restrict__ Hb, u16* __restrict__ Kb,
    u16* __restrict__ Vt)
{
  int b = blockIdx.x;
  if (b < 8192) {
    const float* src = (b < 4096) ? H : Kin;
    u16* dst = (b < 4096) ? Hb : Kb;
    int i = (b & 4095) * 256 + threadIdx.x;   // float4 chunk index, 1M per matrix
    float4 v = ((const float4*)src)[i];
    ushort4 o;
    o.x = f2bf(v.x); o.y = f2bf(v.y); o.z = f2bf(v.z); o.w = f2bf(v.w);
    ((ushort4*)dst)[i] = o;
  } else {
    __shared__ float tile[32][33];
    b -= 8192;
    int c0 = (b & 31) * 32;         // D col tile (D=1024 -> 32 tiles)
    int r0 = (b >> 5) * 32;         // M row tile (M=4096 -> 128 tiles)
    int tx = threadIdx.x & 31, ty = threadIdx.x >> 5;   // (32,8)
    #pragma unroll
    for (int s = 0; s < 32; s += 8)
      tile[ty + s][tx] = V[(size_t)(r0 + ty + s) * 1024 + c0 + tx];
    __syncthreads();
    #pragma unroll
    for (int s = 0; s < 32; s += 8)
      Vt[(size_t)(c0 + ty + s) * 4096 + r0 + tx] = f2bf(tile[tx][ty + s]);
  }
}

// p = exp(exp(s)/L1 * mask) in-place over S (bf16), row sums -> L2.
__global__ __launch_bounds__(256) void softmax2_kernel(
    u16* __restrict__ S, const float* __restrict__ mask,
    const float* __restrict__ L1, float* __restrict__ L2, int M)
{
  int row = blockIdx.x;
  float inv = 1.0f / L1[row];
  u16* srow = S + (size_t)row * M;
  const float* mrow = mask + (size_t)row * M;
  float lsum = 0.f;
  for (int base = threadIdx.x * 16; base < M; base += blockDim.x * 16) {
    u16 sl[16];
    *(uint4*)(sl)     = *(const uint4*)(srow + base);
    *(uint4*)(sl + 8) = *(const uint4*)(srow + base + 8);
    float mv[16];
    #pragma unroll
    for (int q = 0; q < 4; ++q)
      *(float4*)(mv + q * 4) = *(const float4*)(mrow + base + q * 4);
    #pragma unroll
    for (int j = 0; j < 16; ++j) {
      float t = __expf(bf2f(sl[j])) * inv * mv[j];
      float p = __expf(t);
      lsum += p;
      sl[j] = f2bf(p);
    }
    *(uint4*)(srow + base)     = *(uint4*)(sl);
    *(uint4*)(srow + base + 8) = *(uint4*)(sl + 8);
  }
  #pragma unroll
  for (int m = 1; m < 64; m <<= 1) lsum += __shfl_xor(lsum, m, 64);
  __shared__ float wred[4];
  if ((threadIdx.x & 63) == 0) wred[threadIdx.x >> 6] = lsum;
  __syncthreads();
  if (threadIdx.x == 0) L2[row] = wred[0] + wred[1] + wred[2] + wred[3];
}

extern "C" void kernel_launch(void* const* d_in, const int* in_sizes, int n_in,
                              void* d_out, int out_size, void* d_ws, size_t ws_size,
                              hipStream_t stream) {
  const float* H    = (const float*)d_in[0];
  const float* Kin  = (const float*)d_in[1];
  const float* V    = (const float*)d_in[2];
  const float* mask = (const float*)d_in[3];
  float* out = (float*)d_out;

  const int N = 4096, M = 4096, D = 1024;

  // ws: Hb 8MB | Kb 8MB | Vt 8MB | S 32MB | L1 16KB | L2 16KB
  char* ws = (char*)d_ws;
  u16*   Hb = (u16*)(ws);
  u16*   Kb = (u16*)(ws + (8ull << 20));
  u16*   Vt = (u16*)(ws + (16ull << 20));
  u16*   S  = (u16*)(ws + (24ull << 20));
  float* L1 = (float*)(ws + (56ull << 20));
  float* L2 = (float*)(ws + (56ull << 20) + 16384);

  hipMemsetAsync(L1, 0, 32768, stream);                      // L1+L2
  hipMemsetAsync(out, 0, (size_t)N * D * sizeof(float), stream);  // split-K accum

  prep_kernel<<<dim3(12288), dim3(256), 0, stream>>>(H, Kin, V, Hb, Kb, Vt);

  // S = H*K^T/32 (bf16), L1[i] = sum_j exp(S_ij)
  gemm_kernel<0><<<dim3(1024), dim3(256), 0, stream>>>(
      Hb, Kb, S, L1, nullptr, D, D, M);
  // S <- exp(exp(S)/L1 * mask), L2 = row sums
  softmax2_kernel<<<dim3(N), dim3(256), 0, stream>>>(S, mask, L1, L2, M);
  // out += (S_k @ Vt_k^T) / L2   (split-K=4, atomic fp32)
  gemm_kernel<1><<<dim3(1024), dim3(256), 0, stream>>>(
      S, Vt, out, nullptr, L2, M, M, D);
}

// Round 4
// 255.378 us; speedup vs baseline: 1.0354x; 1.0193x over previous
//
#include <hip/hip_runtime.h>
#include <cstdint>

typedef unsigned short u16;
typedef __bf16 bf16x8 __attribute__((ext_vector_type(8)));
typedef float f32x4 __attribute__((ext_vector_type(4)));
typedef unsigned int u32x4 __attribute__((ext_vector_type(4)));

__device__ __forceinline__ float bf2f(u16 h) {
  union { unsigned int u; float f; } v; v.u = ((unsigned int)h) << 16; return v.f;
}
__device__ __forceinline__ u16 f2bf(float f) {
  union { float f; unsigned int u; } v; v.f = f;
  unsigned int u = v.u;
  return (u16)((u + 0x7FFFu + ((u >> 16) & 1u)) >> 16);  // RNE, finite inputs
}

__device__ __forceinline__ void ld_lds16(const void* g, void* l) {
  __builtin_amdgcn_global_load_lds(
      (const __attribute__((address_space(1))) unsigned int*)g,
      (__attribute__((address_space(3))) unsigned int*)l, 16, 0, 0);
}

// ---------------------------------------------------------------------------
// GEMM1: S = (H * K^T)/32 as bf16, L1[row] += sum exp(s). 128x128 tiles,
// grid 1024 flat, XCD region 16 rows x 8 cols. Epilogue transposes through
// LDS for coalesced 16B nontemporal stores.
// ---------------------------------------------------------------------------
__global__ __launch_bounds__(256) void gemm1_kernel(
    const u16* __restrict__ A, const u16* __restrict__ B,
    u16* __restrict__ S, float* __restrict__ L1, int ldA, int ldB, int ldC)
{
  __shared__ u16 smem[128 * 136];           // 34 KB; K-loop uses first 16K u16
  u16* As = smem;                           // 128 x 64
  u16* Bs = smem + 8192;                    // 128 x 64

  const int tid  = threadIdx.x;
  const int lane = tid & 63;
  const int w    = tid >> 6;
  const int wr   = w >> 1;
  const int wc   = w & 1;
  const int quad = lane >> 4;
  const int cIn  = lane & 15;

  const int flat = blockIdx.x;
  const int xcd  = flat & 7;
  const int i    = flat >> 3;
  const int rowBlk = ((xcd >> 2) * 16 + (i & 15)) * 128;
  const int colBlk = ((xcd & 3) * 8 + (i >> 4)) * 128;

  const int lrow   = lane >> 3;
  const int gchunk = (lane & 7) ^ lrow;

  f32x4 acc[4][4];
  #pragma unroll
  for (int a = 0; a < 4; ++a)
    #pragma unroll
    for (int b = 0; b < 4; ++b) acc[a][b] = {0.f, 0.f, 0.f, 0.f};

  for (int k0 = 0; k0 < 1024; k0 += 64) {
    #pragma unroll
    for (int t = 0; t < 4; ++t) {
      int rg = w * 4 + t;
      const u16* ga = A + (size_t)(rowBlk + rg * 8 + lrow) * ldA + k0 + gchunk * 8;
      const u16* gb = B + (size_t)(colBlk + rg * 8 + lrow) * ldB + k0 + gchunk * 8;
      ld_lds16(ga, &As[rg * 512]);
      ld_lds16(gb, &Bs[rg * 512]);
    }
    __syncthreads();

    #pragma unroll
    for (int ks = 0; ks < 2; ++ks) {
      bf16x8 af[4], bfr[4];
      #pragma unroll
      for (int mi = 0; mi < 4; ++mi) {
        int row = wr * 64 + mi * 16 + cIn;
        int ch  = (ks * 4 + quad) ^ (row & 7);
        af[mi]  = *(const bf16x8*)&As[row * 64 + ch * 8];
      }
      #pragma unroll
      for (int ni = 0; ni < 4; ++ni) {
        int row = wc * 64 + ni * 16 + cIn;
        int ch  = (ks * 4 + quad) ^ (row & 7);
        bfr[ni] = *(const bf16x8*)&Bs[row * 64 + ch * 8];
      }
      #pragma unroll
      for (int mi = 0; mi < 4; ++mi)
        #pragma unroll
        for (int ni = 0; ni < 4; ++ni)
          acc[mi][ni] = __builtin_amdgcn_mfma_f32_16x16x32_bf16(
              af[mi], bfr[ni], acc[mi][ni], 0, 0, 0);
    }
    __syncthreads();
  }

  // Epilogue: bf16-round, exp rowsums, stage C tile in LDS (stride 136 to
  // break bank conflicts), then coalesced 16B nontemporal stores.
  const float scale = 0.03125f;  // 1/sqrt(1024)
  #pragma unroll
  for (int mi = 0; mi < 4; ++mi) {
    float rs[4] = {0.f, 0.f, 0.f, 0.f};
    #pragma unroll
    for (int ni = 0; ni < 4; ++ni) {
      int colT = wc * 64 + ni * 16 + cIn;
      #pragma unroll
      for (int r = 0; r < 4; ++r) {
        int rowT = wr * 64 + mi * 16 + quad * 4 + r;
        u16 sb = f2bf(acc[mi][ni][r] * scale);
        smem[rowT * 136 + colT] = sb;
        rs[r] += __expf(bf2f(sb));
      }
    }
    #pragma unroll
    for (int m = 1; m < 16; m <<= 1)
      #pragma unroll
      for (int r = 0; r < 4; ++r) rs[r] += __shfl_xor(rs[r], m, 64);
    if (cIn == 0) {
      #pragma unroll
      for (int r = 0; r < 4; ++r)
        atomicAdd(&L1[rowBlk + wr * 64 + mi * 16 + quad * 4 + r], rs[r]);
    }
  }
  __syncthreads();
  #pragma unroll
  for (int it = 0; it < 8; ++it) {
    int j  = it * 256 + tid;     // 16B chunk id, 2048 total
    int r  = j >> 4;
    int c8 = j & 15;
    u32x4 v = *(const u32x4*)&smem[r * 136 + c8 * 8];
    __builtin_nontemporal_store(
        v, (u32x4*)&S[(size_t)(rowBlk + r) * ldC + colBlk + c8 * 8]);
  }
}

// ---------------------------------------------------------------------------
// GEMM2: out = (P2 @ Vt^T) / L2. 64x128 tiles, full K=4096, grid 512 flat
// (2 blocks/CU), XCD region 8 row-tiles x 8 col-tiles. No atomics.
// ---------------------------------------------------------------------------
__global__ __launch_bounds__(256) void gemm2_kernel(
    const u16* __restrict__ A, const u16* __restrict__ B,
    float* __restrict__ Out, const float* __restrict__ L2,
    int ldA, int ldB, int ldC)
{
  __shared__ u16 As[64 * 64];    // 8 KB
  __shared__ u16 Bs[128 * 64];   // 16 KB

  const int tid  = threadIdx.x;
  const int lane = tid & 63;
  const int w    = tid >> 6;
  const int wrow = w >> 1;       // 0..1 -> 32-row half
  const int wcol = w & 1;        // 0..1 -> 64-col half
  const int quad = lane >> 4;
  const int cIn  = lane & 15;

  const int flat = blockIdx.x;
  const int xcd  = flat & 7;
  const int i    = flat >> 3;              // 0..63
  const int rowBlk = (xcd * 8 + (i & 7)) * 64;
  const int colBlk = (i >> 3) * 128;

  const int lrow   = lane >> 3;
  const int gchunk = (lane & 7) ^ lrow;

  f32x4 acc[2][4];
  #pragma unroll
  for (int a = 0; a < 2; ++a)
    #pragma unroll
    for (int b = 0; b < 4; ++b) acc[a][b] = {0.f, 0.f, 0.f, 0.f};

  for (int k0 = 0; k0 < 4096; k0 += 64) {
    #pragma unroll
    for (int t = 0; t < 2; ++t) {          // As: 8 groups / 4 waves
      int rg = w * 2 + t;
      const u16* ga = A + (size_t)(rowBlk + rg * 8 + lrow) * ldA + k0 + gchunk * 8;
      ld_lds16(ga, &As[rg * 512]);
    }
    #pragma unroll
    for (int t = 0; t < 4; ++t) {          // Bs: 16 groups / 4 waves
      int rg = w * 4 + t;
      const u16* gb = B + (size_t)(colBlk + rg * 8 + lrow) * ldB + k0 + gchunk * 8;
      ld_lds16(gb, &Bs[rg * 512]);
    }
    __syncthreads();

    #pragma unroll
    for (int ks = 0; ks < 2; ++ks) {
      bf16x8 af[2], bfr[4];
      #pragma unroll
      for (int mi = 0; mi < 2; ++mi) {
        int row = wrow * 32 + mi * 16 + cIn;
        int ch  = (ks * 4 + quad) ^ (row & 7);
        af[mi]  = *(const bf16x8*)&As[row * 64 + ch * 8];
      }
      #pragma unroll
      for (int ni = 0; ni < 4; ++ni) {
        int row = wcol * 64 + ni * 16 + cIn;
        int ch  = (ks * 4 + quad) ^ (row & 7);
        bfr[ni] = *(const bf16x8*)&Bs[row * 64 + ch * 8];
      }
      #pragma unroll
      for (int mi = 0; mi < 2; ++mi)
        #pragma unroll
        for (int ni = 0; ni < 4; ++ni)
          acc[mi][ni] = __builtin_amdgcn_mfma_f32_16x16x32_bf16(
              af[mi], bfr[ni], acc[mi][ni], 0, 0, 0);
    }
    __syncthreads();
  }

  #pragma unroll
  for (int mi = 0; mi < 2; ++mi) {
    #pragma unroll
    for (int r = 0; r < 4; ++r) {
      int row   = rowBlk + wrow * 32 + mi * 16 + quad * 4 + r;
      float inv = 1.0f / L2[row];
      #pragma unroll
      for (int ni = 0; ni < 4; ++ni) {
        int col = colBlk + wcol * 64 + ni * 16 + cIn;
        __builtin_nontemporal_store(acc[mi][ni][r] * inv,
                                    &Out[(size_t)row * ldC + col]);
      }
    }
  }
}

// Fused prep: [0,4096) cvt H, [4096,8192) cvt K, [8192,12288) transpose V,
// 12288 zeroes L1+L2.
__global__ __launch_bounds__(256) void prep_kernel(
    const float* __restrict__ H, const float* __restrict__ Kin,
    const float* __restrict__ V, u16* __restrict__ Hb, u16* __restrict__ Kb,
    u16* __restrict__ Vt, float* __restrict__ L1)
{
  int b = blockIdx.x;
  if (b < 8192) {
    const float* src = (b < 4096) ? H : Kin;
    u16* dst = (b < 4096) ? Hb : Kb;
    int i = (b & 4095) * 256 + threadIdx.x;
    float4 v = ((const float4*)src)[i];
    ushort4 o;
    o.x = f2bf(v.x); o.y = f2bf(v.y); o.z = f2bf(v.z); o.w = f2bf(v.w);
    ((ushort4*)dst)[i] = o;
  } else if (b < 12288) {
    __shared__ float tile[32][33];
    b -= 8192;
    int c0 = (b & 31) * 32;
    int r0 = (b >> 5) * 32;
    int tx = threadIdx.x & 31, ty = threadIdx.x >> 5;
    #pragma unroll
    for (int s = 0; s < 32; s += 8)
      tile[ty + s][tx] = V[(size_t)(r0 + ty + s) * 1024 + c0 + tx];
    __syncthreads();
    #pragma unroll
    for (int s = 0; s < 32; s += 8)
      Vt[(size_t)(c0 + ty + s) * 4096 + r0 + tx] = f2bf(tile[tx][ty + s]);
  } else {
    float4* z = (float4*)L1;     // L1 (16KB) + L2 (16KB) contiguous
    #pragma unroll
    for (int q = 0; q < 8; ++q)
      z[q * 256 + threadIdx.x] = {0.f, 0.f, 0.f, 0.f};
  }
}

// p = exp(exp(s)/L1 * mask) in-place over S (bf16), row sums -> L2.
__global__ __launch_bounds__(256) void softmax2_kernel(
    u16* __restrict__ S, const float* __restrict__ mask,
    const float* __restrict__ L1, float* __restrict__ L2, int M)
{
  int row = blockIdx.x;
  float inv = 1.0f / L1[row];
  u16* srow = S + (size_t)row * M;
  const float* mrow = mask + (size_t)row * M;
  float lsum = 0.f;
  for (int base = threadIdx.x * 16; base < M; base += blockDim.x * 16) {
    u16 sl[16];
    *(uint4*)(sl)     = *(const uint4*)(srow + base);
    *(uint4*)(sl + 8) = *(const uint4*)(srow + base + 8);
    float mv[16];
    #pragma unroll
    for (int q = 0; q < 4; ++q)
      *(f32x4*)(mv + q * 4) =
          __builtin_nontemporal_load((const f32x4*)(mrow + base + q * 4));
    #pragma unroll
    for (int j = 0; j < 16; ++j) {
      float t = __expf(bf2f(sl[j])) * inv * mv[j];
      float p = __expf(t);
      lsum += p;
      sl[j] = f2bf(p);
    }
    *(uint4*)(srow + base)     = *(uint4*)(sl);
    *(uint4*)(srow + base + 8) = *(uint4*)(sl + 8);
  }
  #pragma unroll
  for (int m = 1; m < 64; m <<= 1) lsum += __shfl_xor(lsum, m, 64);
  __shared__ float wred[4];
  if ((threadIdx.x & 63) == 0) wred[threadIdx.x >> 6] = lsum;
  __syncthreads();
  if (threadIdx.x == 0) L2[row] = wred[0] + wred[1] + wred[2] + wred[3];
}

extern "C" void kernel_launch(void* const* d_in, const int* in_sizes, int n_in,
                              void* d_out, int out_size, void* d_ws, size_t ws_size,
                              hipStream_t stream) {
  const float* H    = (const float*)d_in[0];
  const float* Kin  = (const float*)d_in[1];
  const float* V    = (const float*)d_in[2];
  const float* mask = (const float*)d_in[3];
  float* out = (float*)d_out;

  const int N = 4096, M = 4096, D = 1024;

  char* ws = (char*)d_ws;
  u16*   Hb = (u16*)(ws);
  u16*   Kb = (u16*)(ws + (8ull << 20));
  u16*   Vt = (u16*)(ws + (16ull << 20));
  u16*   S  = (u16*)(ws + (24ull << 20));
  float* L1 = (float*)(ws + (56ull << 20));
  float* L2 = (float*)(ws + (56ull << 20) + 16384);

  prep_kernel<<<dim3(12289), dim3(256), 0, stream>>>(H, Kin, V, Hb, Kb, Vt, L1);

  gemm1_kernel<<<dim3(1024), dim3(256), 0, stream>>>(Hb, Kb, S, L1, D, D, M);

  softmax2_kernel<<<dim3(N), dim3(256), 0, stream>>>(S, mask, L1, L2, M);

  gemm2_kernel<<<dim3(512), dim3(256), 0, stream>>>(S, Vt, out, L2, M, M, D);
}

// Round 5
// 233.748 us; speedup vs baseline: 1.1313x; 1.0925x over previous
//
#include <hip/hip_runtime.h>
#include <cstdint>

typedef unsigned short u16;
typedef __bf16 bf16x8 __attribute__((ext_vector_type(8)));
typedef float f32x4 __attribute__((ext_vector_type(4)));
typedef unsigned int u32x4 __attribute__((ext_vector_type(4)));

__device__ __forceinline__ float bf2f(u16 h) {
  union { unsigned int u; float f; } v; v.u = ((unsigned int)h) << 16; return v.f;
}
__device__ __forceinline__ u16 f2bf(float f) {
  union { float f; unsigned int u; } v; v.f = f;
  unsigned int u = v.u;
  return (u16)((u + 0x7FFFu + ((u >> 16) & 1u)) >> 16);  // RNE, finite inputs
}

__device__ __forceinline__ void ld_lds16(const void* g, void* l) {
  __builtin_amdgcn_global_load_lds(
      (const __attribute__((address_space(1))) unsigned int*)g,
      (__attribute__((address_space(3))) unsigned int*)l, 16, 0, 0);
}

// ---------------------------------------------------------------------------
// GEMM1: S = (H * K^T)/32 as bf16 (pure GEMM, no row sums). 128x128 tiles,
// grid 1024 flat, XCD region 16 rows x 8 cols. Epilogue transposes 32-row
// bands through an LDS buffer aliased over As/Bs for coalesced 16B stores.
// ---------------------------------------------------------------------------
__global__ __launch_bounds__(256) void gemm1_kernel(
    const u16* __restrict__ A, const u16* __restrict__ B,
    u16* __restrict__ S, int ldA, int ldB, int ldC)
{
  __shared__ u16 smem[128 * 64 * 2];        // 16 KB total
  u16* As = smem;                           // 128 x 64
  u16* Bs = smem + 8192;                    // 128 x 64
  u16* epi = smem;                          // aliased 32 x 136 after K-loop

  const int tid  = threadIdx.x;
  const int lane = tid & 63;
  const int w    = tid >> 6;
  const int wr   = w >> 1;
  const int wc   = w & 1;
  const int quad = lane >> 4;
  const int cIn  = lane & 15;

  const int flat = blockIdx.x;
  const int xcd  = flat & 7;
  const int i    = flat >> 3;
  const int rowBlk = ((xcd >> 2) * 16 + (i & 15)) * 128;
  const int colBlk = ((xcd & 3) * 8 + (i >> 4)) * 128;

  const int lrow   = lane >> 3;
  const int gchunk = (lane & 7) ^ lrow;

  f32x4 acc[4][4];
  #pragma unroll
  for (int a = 0; a < 4; ++a)
    #pragma unroll
    for (int b = 0; b < 4; ++b) acc[a][b] = {0.f, 0.f, 0.f, 0.f};

  for (int k0 = 0; k0 < 1024; k0 += 64) {
    #pragma unroll
    for (int t = 0; t < 4; ++t) {
      int rg = w * 4 + t;
      const u16* ga = A + (size_t)(rowBlk + rg * 8 + lrow) * ldA + k0 + gchunk * 8;
      const u16* gb = B + (size_t)(colBlk + rg * 8 + lrow) * ldB + k0 + gchunk * 8;
      ld_lds16(ga, &As[rg * 512]);
      ld_lds16(gb, &Bs[rg * 512]);
    }
    __syncthreads();

    #pragma unroll
    for (int ks = 0; ks < 2; ++ks) {
      bf16x8 af[4], bfr[4];
      #pragma unroll
      for (int mi = 0; mi < 4; ++mi) {
        int row = wr * 64 + mi * 16 + cIn;
        int ch  = (ks * 4 + quad) ^ (row & 7);
        af[mi]  = *(const bf16x8*)&As[row * 64 + ch * 8];
      }
      #pragma unroll
      for (int ni = 0; ni < 4; ++ni) {
        int row = wc * 64 + ni * 16 + cIn;
        int ch  = (ks * 4 + quad) ^ (row & 7);
        bfr[ni] = *(const bf16x8*)&Bs[row * 64 + ch * 8];
      }
      #pragma unroll
      for (int mi = 0; mi < 4; ++mi)
        #pragma unroll
        for (int ni = 0; ni < 4; ++ni)
          acc[mi][ni] = __builtin_amdgcn_mfma_f32_16x16x32_bf16(
              af[mi], bfr[ni], acc[mi][ni], 0, 0, 0);
    }
    __syncthreads();
  }

  // Epilogue: per mi, stage a 32-row x 128-col band (rows of both wave-halves)
  // in LDS (stride 136 vs banks), then coalesced 16B stores.
  const float scale = 0.03125f;  // 1/sqrt(1024)
  #pragma unroll
  for (int mi = 0; mi < 4; ++mi) {
    #pragma unroll
    for (int ni = 0; ni < 4; ++ni) {
      int colT = wc * 64 + ni * 16 + cIn;
      #pragma unroll
      for (int r = 0; r < 4; ++r) {
        int band = wr * 16 + quad * 4 + r;        // 0..31
        epi[band * 136 + colT] = f2bf(acc[mi][ni][r] * scale);
      }
    }
    __syncthreads();
    #pragma unroll
    for (int it = 0; it < 2; ++it) {
      int j   = it * 256 + tid;                    // 512 chunks of 16B
      int rr  = j >> 4;                            // 0..31
      int c8  = j & 15;
      int grow = rowBlk + (rr >> 4) * 64 + mi * 16 + (rr & 15);
      u32x4 v = *(const u32x4*)&epi[rr * 136 + c8 * 8];
      *(u32x4*)&S[(size_t)grow * ldC + colBlk + c8 * 8] = v;
    }
    __syncthreads();
  }
}

// ---------------------------------------------------------------------------
// GEMM2: out = (P2 @ Vt^T) / L2. 64x128 tiles, BK=128 (two 64-halves, same
// swizzle), full K=4096, grid 512 flat (2 blocks/CU), XCD region 8x8.
// ---------------------------------------------------------------------------
__global__ __launch_bounds__(256) void gemm2_kernel(
    const u16* __restrict__ A, const u16* __restrict__ B,
    float* __restrict__ Out, const float* __restrict__ L2,
    int ldA, int ldB, int ldC)
{
  __shared__ u16 As[2 * 64 * 64];    // 16 KB, half h at h*4096
  __shared__ u16 Bs[2 * 128 * 64];   // 32 KB, half h at h*8192

  const int tid  = threadIdx.x;
  const int lane = tid & 63;
  const int w    = tid >> 6;
  const int wrow = w >> 1;
  const int wcol = w & 1;
  const int quad = lane >> 4;
  const int cIn  = lane & 15;

  const int flat = blockIdx.x;
  const int xcd  = flat & 7;
  const int i    = flat >> 3;              // 0..63
  const int rowBlk = (xcd * 8 + (i & 7)) * 64;
  const int colBlk = (i >> 3) * 128;

  const int lrow   = lane >> 3;
  const int gchunk = (lane & 7) ^ lrow;

  f32x4 acc[2][4];
  #pragma unroll
  for (int a = 0; a < 2; ++a)
    #pragma unroll
    for (int b = 0; b < 4; ++b) acc[a][b] = {0.f, 0.f, 0.f, 0.f};

  for (int k0 = 0; k0 < 4096; k0 += 128) {
    #pragma unroll
    for (int h = 0; h < 2; ++h) {
      int kk = k0 + h * 64;
      #pragma unroll
      for (int t = 0; t < 2; ++t) {
        int rg = w * 2 + t;
        const u16* ga = A + (size_t)(rowBlk + rg * 8 + lrow) * ldA + kk + gchunk * 8;
        ld_lds16(ga, &As[h * 4096 + rg * 512]);
      }
      #pragma unroll
      for (int t = 0; t < 4; ++t) {
        int rg = w * 4 + t;
        const u16* gb = B + (size_t)(colBlk + rg * 8 + lrow) * ldB + kk + gchunk * 8;
        ld_lds16(gb, &Bs[h * 8192 + rg * 512]);
      }
    }
    __syncthreads();

    #pragma unroll
    for (int h = 0; h < 2; ++h) {
      #pragma unroll
      for (int ks = 0; ks < 2; ++ks) {
        bf16x8 af[2], bfr[4];
        #pragma unroll
        for (int mi = 0; mi < 2; ++mi) {
          int row = wrow * 32 + mi * 16 + cIn;
          int ch  = (ks * 4 + quad) ^ (row & 7);
          af[mi]  = *(const bf16x8*)&As[h * 4096 + row * 64 + ch * 8];
        }
        #pragma unroll
        for (int ni = 0; ni < 4; ++ni) {
          int row = wcol * 64 + ni * 16 + cIn;
          int ch  = (ks * 4 + quad) ^ (row & 7);
          bfr[ni] = *(const bf16x8*)&Bs[h * 8192 + row * 64 + ch * 8];
        }
        #pragma unroll
        for (int mi = 0; mi < 2; ++mi)
          #pragma unroll
          for (int ni = 0; ni < 4; ++ni)
            acc[mi][ni] = __builtin_amdgcn_mfma_f32_16x16x32_bf16(
                af[mi], bfr[ni], acc[mi][ni], 0, 0, 0);
      }
    }
    __syncthreads();
  }

  #pragma unroll
  for (int mi = 0; mi < 2; ++mi) {
    #pragma unroll
    for (int r = 0; r < 4; ++r) {
      int row   = rowBlk + wrow * 32 + mi * 16 + quad * 4 + r;
      float inv = 1.0f / L2[row];
      #pragma unroll
      for (int ni = 0; ni < 4; ++ni) {
        int col = colBlk + wcol * 64 + ni * 16 + cIn;
        __builtin_nontemporal_store(acc[mi][ni][r] * inv,
                                    &Out[(size_t)row * ldC + col]);
      }
    }
  }
}

// Fused prep: [0,4096) cvt H, [4096,8192) cvt K, [8192,12288) transpose V.
__global__ __launch_bounds__(256) void prep_kernel(
    const float* __restrict__ H, const float* __restrict__ Kin,
    const float* __restrict__ V, u16* __restrict__ Hb, u16* __restrict__ Kb,
    u16* __restrict__ Vt)
{
  int b = blockIdx.x;
  if (b < 8192) {
    const float* src = (b < 4096) ? H : Kin;
    u16* dst = (b < 4096) ? Hb : Kb;
    int i = (b & 4095) * 256 + threadIdx.x;
    float4 v = ((const float4*)src)[i];
    ushort4 o;
    o.x = f2bf(v.x); o.y = f2bf(v.y); o.z = f2bf(v.z); o.w = f2bf(v.w);
    ((ushort4*)dst)[i] = o;
  } else {
    __shared__ float tile[32][33];
    b -= 8192;
    int c0 = (b & 31) * 32;
    int r0 = (b >> 5) * 32;
    int tx = threadIdx.x & 31, ty = threadIdx.x >> 5;
    #pragma unroll
    for (int s = 0; s < 32; s += 8)
      tile[ty + s][tx] = V[(size_t)(r0 + ty + s) * 1024 + c0 + tx];
    __syncthreads();
    #pragma unroll
    for (int s = 0; s < 32; s += 8)
      Vt[(size_t)(c0 + ty + s) * 4096 + r0 + tx] = f2bf(tile[tx][ty + s]);
  }
}

// softmax2: computes L1 locally (row exp-sum), then p = exp(exp(s)/L1 * mask)
// in-place over S (bf16), row sum -> L2. One block per row, no atomics.
__global__ __launch_bounds__(256) void softmax2_kernel(
    u16* __restrict__ S, const float* __restrict__ mask,
    float* __restrict__ L2, int M)
{
  int row = blockIdx.x;
  u16* srow = S + (size_t)row * M;
  const float* mrow = mask + (size_t)row * M;
  const int base = threadIdx.x * 16;       // M == blockDim.x*16

  u16 sl[16];
  *(uint4*)(sl)     = *(const uint4*)(srow + base);
  *(uint4*)(sl + 8) = *(const uint4*)(srow + base + 8);

  float e[16];
  float s1 = 0.f;
  #pragma unroll
  for (int j = 0; j < 16; ++j) { e[j] = __expf(bf2f(sl[j])); s1 += e[j]; }

  __shared__ float wred[8];
  #pragma unroll
  for (int m = 1; m < 64; m <<= 1) s1 += __shfl_xor(s1, m, 64);
  if ((threadIdx.x & 63) == 0) wred[threadIdx.x >> 6] = s1;
  __syncthreads();
  float inv = 1.0f / (wred[0] + wred[1] + wred[2] + wred[3]);

  float mv[16];
  #pragma unroll
  for (int q = 0; q < 4; ++q)
    *(float4*)(mv + q * 4) = *(const float4*)(mrow + base + q * 4);

  float lsum = 0.f;
  #pragma unroll
  for (int j = 0; j < 16; ++j) {
    float p = __expf(e[j] * inv * mv[j]);
    lsum += p;
    sl[j] = f2bf(p);
  }
  *(uint4*)(srow + base)     = *(uint4*)(sl);
  *(uint4*)(srow + base + 8) = *(uint4*)(sl + 8);

  #pragma unroll
  for (int m = 1; m < 64; m <<= 1) lsum += __shfl_xor(lsum, m, 64);
  if ((threadIdx.x & 63) == 0) wred[4 + (threadIdx.x >> 6)] = lsum;
  __syncthreads();
  if (threadIdx.x == 0) L2[row] = wred[4] + wred[5] + wred[6] + wred[7];
}

extern "C" void kernel_launch(void* const* d_in, const int* in_sizes, int n_in,
                              void* d_out, int out_size, void* d_ws, size_t ws_size,
                              hipStream_t stream) {
  const float* H    = (const float*)d_in[0];
  const float* Kin  = (const float*)d_in[1];
  const float* V    = (const float*)d_in[2];
  const float* mask = (const float*)d_in[3];
  float* out = (float*)d_out;

  const int N = 4096, M = 4096, D = 1024;

  char* ws = (char*)d_ws;
  u16*   Hb = (u16*)(ws);
  u16*   Kb = (u16*)(ws + (8ull << 20));
  u16*   Vt = (u16*)(ws + (16ull << 20));
  u16*   S  = (u16*)(ws + (24ull << 20));
  float* L2 = (float*)(ws + (56ull << 20));

  prep_kernel<<<dim3(12288), dim3(256), 0, stream>>>(H, Kin, V, Hb, Kb, Vt);

  gemm1_kernel<<<dim3(1024), dim3(256), 0, stream>>>(Hb, Kb, S, D, D, M);

  softmax2_kernel<<<dim3(N), dim3(256), 0, stream>>>(S, mask, L2, M);

  gemm2_kernel<<<dim3(512), dim3(256), 0, stream>>>(S, Vt, out, L2, M, M, D);
}